// Round 2
// baseline (1276.720 us; speedup 1.0000x reference)
//
#include <hip/hip_runtime.h>
#include <float.h>
#include <math.h>

#define DIM 512
#define EPSN 1e-12f

typedef _Float16 f16x8 __attribute__((ext_vector_type(8)));
typedef float f32x4 __attribute__((ext_vector_type(4)));

// async global -> LDS, 16B per lane; lds dest = wave-uniform base + lane*16
__device__ inline void gll16(const void* g, void* l) {
  __builtin_amdgcn_global_load_lds(
      (__attribute__((address_space(1))) void*)g,
      (__attribute__((address_space(3))) void*)l, 16, 0, 0);
}

// ---------------- wave (64-lane) sum ----------------
__device__ inline float wave_sum(float v) {
#pragma unroll
  for (int o = 32; o > 0; o >>= 1) v += __shfl_xor(v, o, 64);
  return v;
}

// one wave per emb row: eepair[j] = { sum(embn^2), 1/max(||emb_j||,eps) }
__global__ __launch_bounds__(256) void emb_norm_kernel(
    const float* __restrict__ emb, float2* __restrict__ eepair) {
  int row = blockIdx.x * 4 + (threadIdx.x >> 6);
  int lane = threadIdx.x & 63;
  const float* p = emb + (size_t)row * DIM;
  float x[8];
  float ss = 0.f;
#pragma unroll
  for (int i = 0; i < 8; ++i) { x[i] = p[i * 64 + lane]; ss += x[i] * x[i]; }
  ss = wave_sum(ss);
  float d = fmaxf(sqrtf(ss), EPSN);
  float ee = 0.f;
#pragma unroll
  for (int i = 0; i < 8; ++i) { float y = x[i] / d; ee += y * y; }
  ee = wave_sum(ee);
  if (lane == 0) eepair[row] = make_float2(ee, 1.0f / d);
}

// one wave per z row: zinv[n] = 1/max(||z_n||,eps)
__global__ __launch_bounds__(256) void z_norm_kernel(
    const float* __restrict__ z, float* __restrict__ zinv) {
  int row = blockIdx.x * 4 + (threadIdx.x >> 6);
  int lane = threadIdx.x & 63;
  const float* p = z + (size_t)row * DIM;
  float ss = 0.f;
#pragma unroll
  for (int i = 0; i < 8; ++i) { float v = p[i * 64 + lane]; ss += v * v; }
  ss = wave_sum(ss);
  if (lane == 0) zinv[row] = 1.0f / fmaxf(sqrtf(ss), EPSN);
}

// ---------------- emb -> swizzled hi/lo fp16 (LDS tile order) ----------------
// swz layout: chunk c = (tile16 * 16 + kc) * 2 + half, each chunk = 64 lanes
// x 8 f16 (1 KB); element (lane = quad*16+col, j) = emb[tile16*16+col]
// [kc*32 + quad*8 + j], split hi/lo. This IS the MFMA B-fragment order, so
// dist staging is a plain linear async copy and all LDS traffic is
// contiguous-per-lane (conflict-free).
__global__ __launch_bounds__(256) void emb_split_kernel(
    const float* __restrict__ emb, _Float16* __restrict__ swz) {
  int g = blockIdx.x * 256 + threadIdx.x;  // = t*1024 + kc*64 + lane
  int lane = g & 63;
  int kc = (g >> 6) & 15;
  int t = g >> 10;
  int code = t * 16 + (lane & 15);
  int k0 = kc * 32 + (lane >> 4) * 8;
  const float* src = emb + (size_t)code * DIM + k0;
  float4 a = *(const float4*)src;
  float4 b = *(const float4*)(src + 4);
  float v[8] = {a.x, a.y, a.z, a.w, b.x, b.y, b.z, b.w};
  f16x8 h, l;
#pragma unroll
  for (int k = 0; k < 8; ++k) {
    _Float16 hh = (_Float16)v[k];
    h[k] = hh;
    l[k] = (_Float16)(v[k] - (float)hh);
  }
  size_t cbase = ((size_t)(t * 16 + kc) * 2) * 512;  // f16 units
  *(f16x8*)&swz[cbase + lane * 8] = h;
  *(f16x8*)&swz[cbase + 512 + lane * 8] = l;
}

// ---------------- MFMA distance + argmin ----------------
// 256 blocks x 256 threads (4 waves, 1 wave/SIMD). Each wave owns 32 rows as
// two 16-row MFMA blocks with persistent hi/lo fp16 A fragments; each B
// fragment pair feeds 6 MFMAs (hh, lh, hl ~= fp32-exact dot).
//
// Pipeline (T3+T4): 16-code tiles (32 KB + 128B ep), 4 LDS buffers, prefetch
// depth 3, raw s_barrier + counted s_waitcnt vmcnt(18) -- never a vmcnt(0)
// drain in steady state; DMA for tiles t+1..t+3 stays in flight across
// barriers. eepair is delivered through the SAME gll16 stream into a per-wave
// LDS slot so the K-loop has zero vector-memory consumers (an in-loop global
// load would force an ordered-queue drain of all prefetches before its use).
// Tile order is rotated per-XCD (T1) so the 8 XCDs stream disjoint swz
// regions (spreads L3 slice load; within-XCD order is shared for L2
// multicast). Rotation requires an explicit index tie-break to keep argmin's
// first-index semantics.
#define MFMA16(A, B, C) __builtin_amdgcn_mfma_f32_16x16x32_f16(A, B, C, 0, 0, 0)

__global__ __launch_bounds__(256, 1) void dist_argmin_kernel(
    const float* __restrict__ z, const _Float16* __restrict__ swz,
    const float2* __restrict__ eepair, const float* __restrict__ zinv,
    int ne, int* __restrict__ idxw, float* __restrict__ counts,
    float* __restrict__ out_idx) {
  __shared__ __attribute__((aligned(16))) _Float16 Bb[4][16384];  // 4 x 32 KB
  __shared__ __attribute__((aligned(16))) float Bep[4][1024];     // 4 x 4 KB

  const int tid = threadIdx.x;
  const int wave = tid >> 6;
  const int lane = tid & 63;
  const int col = lane & 15;
  const int quad = lane >> 4;
  const int r0 = blockIdx.x * 128 + wave * 32;

  // persistent A fragments (hi/lo) for two 16-row blocks
  f16x8 Ah[2][16], Al[2][16];
#pragma unroll
  for (int rb = 0; rb < 2; ++rb) {
    const float* zp = z + (size_t)(r0 + rb * 16 + col) * DIM + quad * 8;
#pragma unroll
    for (int kc = 0; kc < 16; ++kc) {
      float4 a = *(const float4*)(zp + kc * 32);
      float4 b = *(const float4*)(zp + kc * 32 + 4);
      float v[8] = {a.x, a.y, a.z, a.w, b.x, b.y, b.z, b.w};
#pragma unroll
      for (int k = 0; k < 8; ++k) {
        _Float16 h = (_Float16)v[k];
        Ah[rb][kc][k] = h;
        Al[rb][kc][k] = (_Float16)(v[k] - (float)h);
      }
    }
  }

  float zr[2][4];
#pragma unroll
  for (int rb = 0; rb < 2; ++rb)
#pragma unroll
    for (int i = 0; i < 4; ++i)
      zr[rb][i] = zinv[r0 + rb * 16 + quad * 4 + i];

  float best[2][4] = {{FLT_MAX, FLT_MAX, FLT_MAX, FLT_MAX},
                      {FLT_MAX, FLT_MAX, FLT_MAX, FLT_MAX}};
  int bidx[2][4] = {{0, 0, 0, 0}, {0, 0, 0, 0}};

  const int ntiles = ne / 16;                       // 512 16-code tiles
  const int off = (blockIdx.x & 7) * (ntiles >> 3); // XCD tile-order rotation

  // stage tile t (physical tile (t+off)&511) into buffer t&3:
  // 8 x 1KB B chunks + 1 x ep chunk (16 float2, lanes 0-7 carry the data,
  // replicated 8x in the wave's 1KB LDS slot). 9 gll16 per wave per tile.
  auto issue = [&](int t) {
    const int g = (t + off) & (ntiles - 1);
    const int buf = t & 3;
    const _Float16* gb =
        swz + (size_t)g * 16384 + (wave * 8) * 512 + lane * 8;
    _Float16* lb = &Bb[buf][(wave * 8) * 512 + lane * 8];
#pragma unroll
    for (int i = 0; i < 8; ++i) gll16(gb + i * 512, lb + i * 512);
    const float* ge = (const float*)eepair + (size_t)g * 32 + (lane & 7) * 4;
    gll16(ge, &Bep[buf][wave * 256 + lane * 4]);
  };

  issue(0);
  issue(1);
  issue(2);  // 27 loads in flight per wave

  for (int t = 0; t < ntiles; ++t) {
    // counted wait: oldest 9 (tile t) complete; t+1..t+3 stay in flight.
    if (t < ntiles - 2)
      asm volatile("s_waitcnt vmcnt(18)" ::: "memory");
    else if (t == ntiles - 2)
      asm volatile("s_waitcnt vmcnt(9)" ::: "memory");
    else
      asm volatile("s_waitcnt vmcnt(0)" ::: "memory");
    __builtin_amdgcn_s_barrier();
    __builtin_amdgcn_sched_barrier(0);

    if (t + 3 < ntiles) issue(t + 3);  // overwrites buf (t-1)&3: all waves
                                       // finished reading it before barrier

    const int buf = t & 3;
    const int g = (t + off) & (ntiles - 1);
    float2 ep = *(const float2*)&Bep[buf][wave * 256 + col * 2];

    f32x4 acc[2][3];
#pragma unroll
    for (int rb = 0; rb < 2; ++rb)
#pragma unroll
      for (int a = 0; a < 3; ++a) acc[rb][a] = (f32x4){0.f, 0.f, 0.f, 0.f};

    const _Float16* bp = &Bb[buf][lane * 8];
    __builtin_amdgcn_s_setprio(1);
#pragma unroll
    for (int kc = 0; kc < 16; ++kc) {
      f16x8 bh = *(const f16x8*)(bp + (kc * 2) * 512);
      f16x8 bl = *(const f16x8*)(bp + (kc * 2 + 1) * 512);
      acc[0][0] = MFMA16(Ah[0][kc], bh, acc[0][0]);
      acc[1][0] = MFMA16(Ah[1][kc], bh, acc[1][0]);
      acc[0][1] = MFMA16(Al[0][kc], bh, acc[0][1]);
      acc[1][1] = MFMA16(Al[1][kc], bh, acc[1][1]);
      acc[0][2] = MFMA16(Ah[0][kc], bl, acc[0][2]);
      acc[1][2] = MFMA16(Ah[1][kc], bl, acc[1][2]);
    }
    __builtin_amdgcn_s_setprio(0);

    // epilogue: score = ee_j - 2*einv_j*zinv_r*dot; tie-break on lowest j
    // (required because rotation visits codes out of order)
    float w2 = 2.0f * ep.y;
    int j = g * 16 + col;
#pragma unroll
    for (int rb = 0; rb < 2; ++rb)
#pragma unroll
      for (int i = 0; i < 4; ++i) {
        float d = acc[rb][0][i] + acc[rb][1][i] + acc[rb][2][i];
        float sc = ep.x - w2 * zr[rb][i] * d;
        if (sc < best[rb][i] ||
            (sc == best[rb][i] && j < bidx[rb][i])) {
          best[rb][i] = sc;
          bidx[rb][i] = j;
        }
      }
  }

  // merge across the 16 columns within each quad (xor 1,2,4,8 stays in quad)
#pragma unroll
  for (int rb = 0; rb < 2; ++rb)
#pragma unroll
    for (int i = 0; i < 4; ++i) {
      float bs = best[rb][i];
      int bj = bidx[rb][i];
#pragma unroll
      for (int offm = 1; offm < 16; offm <<= 1) {
        float os = __shfl_xor(bs, offm, 64);
        int oi = __shfl_xor(bj, offm, 64);
        if (os < bs || (os == bs && oi < bj)) { bs = os; bj = oi; }
      }
      if (col == 0) {
        int row = r0 + rb * 16 + quad * 4 + i;
        idxw[row] = bj;
        out_idx[row] = (float)bj;
        atomicAdd(&counts[bj], 1.0f);
      }
    }
}

// one wave per row: z_q_st = normalize(q); per-block loss partial
__global__ __launch_bounds__(256) void finalize_rows_kernel(
    const float* __restrict__ z, const float* __restrict__ emb,
    const int* __restrict__ idxw, const float* __restrict__ zinv,
    float* __restrict__ out_zq, float* __restrict__ lpart) {
  __shared__ float red[4];
  int row = blockIdx.x * 4 + (threadIdx.x >> 6);
  int lane = threadIdx.x & 63;
  int j = idxw[row];
  const float* zp = z + (size_t)row * DIM;
  const float* qp = emb + (size_t)j * DIM;
  float zl[8], ql[8], tl[8];
  float st = 0.f, sq = 0.f;
#pragma unroll
  for (int i = 0; i < 8; ++i) {
    int k = i * 64 + lane;
    float zv = zp[k], qv = qp[k];
    float t = zv + (qv - zv);  // straight-through, literal arithmetic
    zl[i] = zv; ql[i] = qv; tl[i] = t;
    st += t * t;
    sq += qv * qv;
  }
  st = wave_sum(st);
  sq = wave_sum(sq);
  float dt = fmaxf(sqrtf(st), EPSN);
  float dq = fmaxf(sqrtf(sq), EPSN);
  float zi = zinv[row];
  float lp = 0.f;
#pragma unroll
  for (int i = 0; i < 8; ++i) {
    int k = i * 64 + lane;
    out_zq[(size_t)row * DIM + k] = tl[i] / dt;
    float e = ql[i] / dq - zl[i] * zi;
    lp += e * e;
  }
  lp = wave_sum(lp);
  if (lane == 0) red[threadIdx.x >> 6] = lp;
  __syncthreads();
  if (threadIdx.x == 0) lpart[blockIdx.x] = red[0] + red[1] + red[2] + red[3];
}

// single block: loss scalar (sum of block partials) + perplexity from counts
__global__ __launch_bounds__(256) void scalars_kernel(
    const float* __restrict__ counts, const float* __restrict__ lpart,
    int ne, int nblk, float inv_n, float inv_total,
    float* __restrict__ out_loss, float* __restrict__ out_perp) {
  __shared__ float red[8];
  int tid = threadIdx.x;
  float s = 0.f;
  for (int jj = tid; jj < ne; jj += 256) {
    float p = counts[jj] * inv_n;
    s += p * logf(p + 1e-10f);
  }
  float l = 0.f;
  for (int jj = tid; jj < nblk; jj += 256) l += lpart[jj];
  s = wave_sum(s);
  l = wave_sum(l);
  if ((tid & 63) == 0) { red[tid >> 6] = s; red[4 + (tid >> 6)] = l; }
  __syncthreads();
  if (tid == 0) {
    float t = red[0] + red[1] + red[2] + red[3];
    float lt = red[4] + red[5] + red[6] + red[7];
    *out_perp = expf(-t);
    *out_loss = 1.25f * lt * inv_total;  // (1+BETA)*mean, sg() identity fwd
  }
}

extern "C" void kernel_launch(void* const* d_in, const int* in_sizes, int n_in,
                              void* d_out, int out_size, void* d_ws, size_t ws_size,
                              hipStream_t stream) {
  const float* z = (const float*)d_in[0];
  const float* emb = (const float*)d_in[1];
  float* out = (float*)d_out;
  float* ws = (float*)d_ws;

  const int nrows = in_sizes[0] / DIM;  // 32768
  const int ne = in_sizes[1] / DIM;     // 8192
  const int nfin = nrows / 4;           // finalize blocks

  // workspace layout (floats)
  float2* eepair = (float2*)ws;                  // ne float2
  float* zinv = ws + 2 * ne;                     // nrows
  int* idxw = (int*)(ws + 2 * ne + nrows);       // nrows
  float* counts = ws + 2 * ne + 2 * nrows;       // ne
  float* lpart = counts + ne;                    // nfin
  _Float16* swz = (_Float16*)(lpart + nfin);     // ne*1024 f16 (~16.8 MB)

  float* out_zq = out + 1;
  float* out_idx = out + 1 + (size_t)nrows * DIM;
  float* out_perp = out + (size_t)out_size - 1;

  hipMemsetAsync(counts, 0, ne * sizeof(float), stream);
  emb_norm_kernel<<<ne / 4, 256, 0, stream>>>(emb, eepair);
  z_norm_kernel<<<nrows / 4, 256, 0, stream>>>(z, zinv);
  emb_split_kernel<<<ne * 64 / 256, 256, 0, stream>>>(emb, swz);
  dist_argmin_kernel<<<nrows / 128, 256, 0, stream>>>(z, swz, eepair, zinv, ne,
                                                      idxw, counts, out_idx);
  finalize_rows_kernel<<<nfin, 256, 0, stream>>>(z, emb, idxw, zinv,
                                                 out_zq, lpart);
  scalars_kernel<<<1, 256, 0, stream>>>(counts, lpart, ne, nfin,
                                        1.0f / (float)nrows,
                                        1.0f / (float)((size_t)nrows * DIM),
                                        out, out_perp);
}

// Round 3
// 1058.212 us; speedup vs baseline: 1.2065x; 1.2065x over previous
//
#include <hip/hip_runtime.h>
#include <float.h>
#include <math.h>

#define DIM 512
#define EPSN 1e-12f

typedef _Float16 f16x8 __attribute__((ext_vector_type(8)));
typedef float f32x4 __attribute__((ext_vector_type(4)));

// async global -> LDS, 16B per lane; lds dest = wave-uniform base + lane*16
__device__ inline void gll16(const void* g, void* l) {
  __builtin_amdgcn_global_load_lds(
      (__attribute__((address_space(1))) void*)g,
      (__attribute__((address_space(3))) void*)l, 16, 0, 0);
}

// ---------------- wave (64-lane) sum ----------------
__device__ inline float wave_sum(float v) {
#pragma unroll
  for (int o = 32; o > 0; o >>= 1) v += __shfl_xor(v, o, 64);
  return v;
}

// one wave per emb row: eepair[j] = { sum(embn^2), 1/max(||emb_j||,eps) }
__global__ __launch_bounds__(256) void emb_norm_kernel(
    const float* __restrict__ emb, float2* __restrict__ eepair) {
  int row = blockIdx.x * 4 + (threadIdx.x >> 6);
  int lane = threadIdx.x & 63;
  const float* p = emb + (size_t)row * DIM;
  float x[8];
  float ss = 0.f;
#pragma unroll
  for (int i = 0; i < 8; ++i) { x[i] = p[i * 64 + lane]; ss += x[i] * x[i]; }
  ss = wave_sum(ss);
  float d = fmaxf(sqrtf(ss), EPSN);
  float ee = 0.f;
#pragma unroll
  for (int i = 0; i < 8; ++i) { float y = x[i] / d; ee += y * y; }
  ee = wave_sum(ee);
  if (lane == 0) eepair[row] = make_float2(ee, 1.0f / d);
}

// one wave per z row: zinv[n] = 1/max(||z_n||,eps)  (used by finalize only)
__global__ __launch_bounds__(256) void z_norm_kernel(
    const float* __restrict__ z, float* __restrict__ zinv) {
  int row = blockIdx.x * 4 + (threadIdx.x >> 6);
  int lane = threadIdx.x & 63;
  const float* p = z + (size_t)row * DIM;
  float ss = 0.f;
#pragma unroll
  for (int i = 0; i < 8; ++i) { float v = p[i * 64 + lane]; ss += v * v; }
  ss = wave_sum(ss);
  if (lane == 0) zinv[row] = 1.0f / fmaxf(sqrtf(ss), EPSN);
}

// ---------------- emb -> swizzled hi/lo fp16 of (embn * 1024) --------------
// swz layout: chunk c = (tile16 * 16 + kc) * 2 + half, each chunk = 64 lanes
// x 8 f16 (1 KB); element (lane = quad*16+col, j) = embn[tile16*16+col]
// [kc*32 + quad*8 + j] * 1024, split hi/lo. Storing the NORMALIZED codebook
// (x1024 keeps the lo half clear of fp16 subnormals) makes
// argmin(distance) == argmax(dot): ||zn||^2 is per-row constant and
// ||embn||^2 = 1 +- 2^-23, perturbation ~100x below the fp16 hi/lo dot
// error that already passes. This removes eepair/zinv from the hot loop
// entirely -> zero vector-memory consumers there.
__global__ __launch_bounds__(256) void emb_split_kernel(
    const float* __restrict__ emb, const float2* __restrict__ eepair,
    _Float16* __restrict__ swz) {
  int g = blockIdx.x * 256 + threadIdx.x;  // = t*1024 + kc*64 + lane
  int lane = g & 63;
  int kc = (g >> 6) & 15;
  int t = g >> 10;
  int code = t * 16 + (lane & 15);
  int k0 = kc * 32 + (lane >> 4) * 8;
  float sc = 1024.0f * eepair[code].y;
  const float* src = emb + (size_t)code * DIM + k0;
  float4 a = *(const float4*)src;
  float4 b = *(const float4*)(src + 4);
  float v[8] = {a.x, a.y, a.z, a.w, b.x, b.y, b.z, b.w};
  f16x8 h, l;
#pragma unroll
  for (int k = 0; k < 8; ++k) {
    float vs = v[k] * sc;
    _Float16 hh = (_Float16)vs;
    h[k] = hh;
    l[k] = (_Float16)(vs - (float)hh);
  }
  size_t cbase = ((size_t)(t * 16 + kc) * 2) * 512;  // f16 units
  *(f16x8*)&swz[cbase + lane * 8] = h;
  *(f16x8*)&swz[cbase + 512 + lane * 8] = l;
}

// ---------------- MFMA dot + per-partition argmax ----------------
// Delivery-rate analysis (r0/r2): both prior versions ran at ~6 B/cyc/CU of
// global->LDS DMA == 16.8MB/block / dur. That matches ~20 in-service lines
// per wave at L3-class (~900cy) latency; m97's 22 B/cyc shows the path does
// 4x more when the source is cache-hot. Fix: partition the codebook 8 ways,
// partition = blockIdx & 7 == XCD id under round-robin dispatch. Each XCD's
// working set is then 1024 codes = 2.1MB < 4MB L2 -> all re-reads are L2
// hits (~200cy) regardless of inter-block drift -> ~25 B/cyc > the 17.6
// needed to be MFMA-bound. DMA bytes per CU unchanged. Wrong-mapping worst
// case degrades to the old rate, not below. A merge kernel folds the 8
// per-partition (score, idx) partials per row.
//
// Within-block structure is the round-2-proven one: 4 waves x 32 rows,
// persistent hi/lo A fragments, 16-code tiles (32KB), 4 LDS buffers,
// depth-3 prefetch, counted vmcnt (16/8/0), raw s_barrier, setprio around
// the MFMA cluster. 8 gll16 per wave per tile, no other vmem in the loop.
#define MFMA16(A, B, C) __builtin_amdgcn_mfma_f32_16x16x32_f16(A, B, C, 0, 0, 0)

__global__ __launch_bounds__(256, 1) void dist_argmin_kernel(
    const float* __restrict__ z, const _Float16* __restrict__ swz,
    int ne, int nrows, float* __restrict__ pscore, int* __restrict__ pidx) {
  __shared__ __attribute__((aligned(16))) _Float16 Bb[4][16384];  // 4 x 32 KB

  const int tid = threadIdx.x;
  const int wave = tid >> 6;
  const int lane = tid & 63;
  const int col = lane & 15;
  const int quad = lane >> 4;
  const int part = blockIdx.x & 7;          // codebook partition == XCD (rr)
  const int r0 = (blockIdx.x >> 3) * 128 + wave * 32;
  const int ntl = ne >> 7;                  // 64 16-code tiles per partition
  const int tbase = part * ntl;             // global tile base

  // persistent A fragments (hi/lo) for two 16-row blocks, from RAW z
  // (argmax of dot is invariant to the positive per-row scale zinv)
  f16x8 Ah[2][16], Al[2][16];
#pragma unroll
  for (int rb = 0; rb < 2; ++rb) {
    const float* zp = z + (size_t)(r0 + rb * 16 + col) * DIM + quad * 8;
#pragma unroll
    for (int kc = 0; kc < 16; ++kc) {
      float4 a = *(const float4*)(zp + kc * 32);
      float4 b = *(const float4*)(zp + kc * 32 + 4);
      float v[8] = {a.x, a.y, a.z, a.w, b.x, b.y, b.z, b.w};
#pragma unroll
      for (int k = 0; k < 8; ++k) {
        _Float16 h = (_Float16)v[k];
        Ah[rb][kc][k] = h;
        Al[rb][kc][k] = (_Float16)(v[k] - (float)h);
      }
    }
  }

  float best[2][4] = {{-FLT_MAX, -FLT_MAX, -FLT_MAX, -FLT_MAX},
                      {-FLT_MAX, -FLT_MAX, -FLT_MAX, -FLT_MAX}};
  int bidx[2][4] = {{0, 0, 0, 0}, {0, 0, 0, 0}};

  // stage tile t (global tile tbase+t) into buffer t&3: wave covers chunks
  // wave*8 .. wave*8+7 (8 x 1KB). 8 gll16 per wave per tile, nothing else.
  auto issue = [&](int t) {
    const int buf = t & 3;
    const _Float16* gb =
        swz + (size_t)(tbase + t) * 16384 + (wave * 8) * 512 + lane * 8;
    _Float16* lb = &Bb[buf][(wave * 8) * 512 + lane * 8];
#pragma unroll
    for (int i = 0; i < 8; ++i) gll16(gb + i * 512, lb + i * 512);
  };

  issue(0);
  issue(1);
  issue(2);  // 24 loads in flight per wave

  for (int t = 0; t < ntl; ++t) {
    // counted wait: oldest 8 (tile t) complete; t+1..t+3 stay in flight.
    if (t < ntl - 2)
      asm volatile("s_waitcnt vmcnt(16)" ::: "memory");
    else if (t == ntl - 2)
      asm volatile("s_waitcnt vmcnt(8)" ::: "memory");
    else
      asm volatile("s_waitcnt vmcnt(0)" ::: "memory");
    __builtin_amdgcn_s_barrier();
    __builtin_amdgcn_sched_barrier(0);

    if (t + 3 < ntl) issue(t + 3);  // overwrites buf (t-1)&3: all waves
                                    // finished reading it before barrier

    const int buf = t & 3;

    f32x4 acc[2][3];
#pragma unroll
    for (int rb = 0; rb < 2; ++rb)
#pragma unroll
      for (int a = 0; a < 3; ++a) acc[rb][a] = (f32x4){0.f, 0.f, 0.f, 0.f};

    const _Float16* bp = &Bb[buf][lane * 8];
    __builtin_amdgcn_s_setprio(1);
#pragma unroll
    for (int kc = 0; kc < 16; ++kc) {
      f16x8 bh = *(const f16x8*)(bp + (kc * 2) * 512);
      f16x8 bl = *(const f16x8*)(bp + (kc * 2 + 1) * 512);
      acc[0][0] = MFMA16(Ah[0][kc], bh, acc[0][0]);
      acc[1][0] = MFMA16(Ah[1][kc], bh, acc[1][0]);
      acc[0][1] = MFMA16(Al[0][kc], bh, acc[0][1]);
      acc[1][1] = MFMA16(Al[1][kc], bh, acc[1][1]);
      acc[0][2] = MFMA16(Ah[0][kc], bl, acc[0][2]);
      acc[1][2] = MFMA16(Ah[1][kc], bl, acc[1][2]);
    }
    __builtin_amdgcn_s_setprio(0);

    // epilogue: pure argmax of the dot. Tiles ascend in j within the
    // partition, so strict '>' keeps the first (lowest) index on ties.
    int j = (tbase + t) * 16 + col;
#pragma unroll
    for (int rb = 0; rb < 2; ++rb)
#pragma unroll
      for (int i = 0; i < 4; ++i) {
        float d = acc[rb][0][i] + acc[rb][1][i] + acc[rb][2][i];
        if (d > best[rb][i]) { best[rb][i] = d; bidx[rb][i] = j; }
      }
  }

  // merge across the 16 columns within each quad (xor 1,2,4,8 stays in quad)
#pragma unroll
  for (int rb = 0; rb < 2; ++rb)
#pragma unroll
    for (int i = 0; i < 4; ++i) {
      float bs = best[rb][i];
      int bj = bidx[rb][i];
#pragma unroll
      for (int offm = 1; offm < 16; offm <<= 1) {
        float os = __shfl_xor(bs, offm, 64);
        int oi = __shfl_xor(bj, offm, 64);
        if (os > bs || (os == bs && oi < bj)) { bs = os; bj = oi; }
      }
      if (col == 0) {
        int row = r0 + rb * 16 + quad * 4 + i;
        pscore[(size_t)part * nrows + row] = bs;
        pidx[(size_t)part * nrows + row] = bj;
      }
    }
}

// fold the 8 per-partition partials per row; ascending p + strict '>'
// preserves global first-index semantics (partitions hold ascending ranges)
__global__ __launch_bounds__(256) void merge_kernel(
    const float* __restrict__ pscore, const int* __restrict__ pidx,
    int nrows, int* __restrict__ idxw, float* __restrict__ counts,
    float* __restrict__ out_idx) {
  int row = blockIdx.x * 256 + threadIdx.x;
  float bs = pscore[row];
  int bj = pidx[row];
#pragma unroll
  for (int p = 1; p < 8; ++p) {
    float s = pscore[(size_t)p * nrows + row];
    int j2 = pidx[(size_t)p * nrows + row];
    if (s > bs || (s == bs && j2 < bj)) { bs = s; bj = j2; }
  }
  idxw[row] = bj;
  out_idx[row] = (float)bj;
  atomicAdd(&counts[bj], 1.0f);
}

// one wave per row: z_q_st = normalize(q); per-block loss partial
__global__ __launch_bounds__(256) void finalize_rows_kernel(
    const float* __restrict__ z, const float* __restrict__ emb,
    const int* __restrict__ idxw, const float* __restrict__ zinv,
    float* __restrict__ out_zq, float* __restrict__ lpart) {
  __shared__ float red[4];
  int row = blockIdx.x * 4 + (threadIdx.x >> 6);
  int lane = threadIdx.x & 63;
  int j = idxw[row];
  const float* zp = z + (size_t)row * DIM;
  const float* qp = emb + (size_t)j * DIM;
  float zl[8], ql[8], tl[8];
  float st = 0.f, sq = 0.f;
#pragma unroll
  for (int i = 0; i < 8; ++i) {
    int k = i * 64 + lane;
    float zv = zp[k], qv = qp[k];
    float t = zv + (qv - zv);  // straight-through, literal arithmetic
    zl[i] = zv; ql[i] = qv; tl[i] = t;
    st += t * t;
    sq += qv * qv;
  }
  st = wave_sum(st);
  sq = wave_sum(sq);
  float dt = fmaxf(sqrtf(st), EPSN);
  float dq = fmaxf(sqrtf(sq), EPSN);
  float zi = zinv[row];
  float lp = 0.f;
#pragma unroll
  for (int i = 0; i < 8; ++i) {
    int k = i * 64 + lane;
    out_zq[(size_t)row * DIM + k] = tl[i] / dt;
    float e = ql[i] / dq - zl[i] * zi;
    lp += e * e;
  }
  lp = wave_sum(lp);
  if (lane == 0) red[threadIdx.x >> 6] = lp;
  __syncthreads();
  if (threadIdx.x == 0) lpart[blockIdx.x] = red[0] + red[1] + red[2] + red[3];
}

// single block: loss scalar (sum of block partials) + perplexity from counts
__global__ __launch_bounds__(256) void scalars_kernel(
    const float* __restrict__ counts, const float* __restrict__ lpart,
    int ne, int nblk, float inv_n, float inv_total,
    float* __restrict__ out_loss, float* __restrict__ out_perp) {
  __shared__ float red[8];
  int tid = threadIdx.x;
  float s = 0.f;
  for (int jj = tid; jj < ne; jj += 256) {
    float p = counts[jj] * inv_n;
    s += p * logf(p + 1e-10f);
  }
  float l = 0.f;
  for (int jj = tid; jj < nblk; jj += 256) l += lpart[jj];
  s = wave_sum(s);
  l = wave_sum(l);
  if ((tid & 63) == 0) { red[tid >> 6] = s; red[4 + (tid >> 6)] = l; }
  __syncthreads();
  if (tid == 0) {
    float t = red[0] + red[1] + red[2] + red[3];
    float lt = red[4] + red[5] + red[6] + red[7];
    *out_perp = expf(-t);
    *out_loss = 1.25f * lt * inv_total;  // (1+BETA)*mean, sg() identity fwd
  }
}

extern "C" void kernel_launch(void* const* d_in, const int* in_sizes, int n_in,
                              void* d_out, int out_size, void* d_ws, size_t ws_size,
                              hipStream_t stream) {
  const float* z = (const float*)d_in[0];
  const float* emb = (const float*)d_in[1];
  float* out = (float*)d_out;
  float* ws = (float*)d_ws;

  const int nrows = in_sizes[0] / DIM;  // 32768
  const int ne = in_sizes[1] / DIM;     // 8192
  const int nfin = nrows / 4;           // finalize blocks

  // workspace layout (floats)
  float2* eepair = (float2*)ws;                  // ne float2
  float* zinv = ws + 2 * ne;                     // nrows
  int* idxw = (int*)(ws + 2 * ne + nrows);       // nrows
  float* counts = ws + 2 * ne + 2 * nrows;       // ne
  float* lpart = counts + ne;                    // nfin
  float* pscore = lpart + nfin;                  // 8 * nrows
  int* pidx = (int*)(pscore + 8 * (size_t)nrows);// 8 * nrows
  _Float16* swz = (_Float16*)(pidx + 8 * (size_t)nrows);  // ne*1024 f16

  float* out_zq = out + 1;
  float* out_idx = out + 1 + (size_t)nrows * DIM;
  float* out_perp = out + (size_t)out_size - 1;

  hipMemsetAsync(counts, 0, ne * sizeof(float), stream);
  emb_norm_kernel<<<ne / 4, 256, 0, stream>>>(emb, eepair);
  z_norm_kernel<<<nrows / 4, 256, 0, stream>>>(z, zinv);
  emb_split_kernel<<<ne * 64 / 256, 256, 0, stream>>>(emb, eepair, swz);
  dist_argmin_kernel<<<(nrows / 128) * 8, 256, 0, stream>>>(z, swz, ne, nrows,
                                                            pscore, pidx);
  merge_kernel<<<nrows / 256, 256, 0, stream>>>(pscore, pidx, nrows,
                                                idxw, counts, out_idx);
  finalize_rows_kernel<<<nfin, 256, 0, stream>>>(z, emb, idxw, zinv,
                                                 out_zq, lpart);
  scalars_kernel<<<1, 256, 0, stream>>>(counts, lpart, ne, nfin,
                                        1.0f / (float)nrows,
                                        1.0f / (float)((size_t)nrows * DIM),
                                        out, out_perp);
}

// Round 5
// 900.582 us; speedup vs baseline: 1.4177x; 1.1750x over previous
//
#include <hip/hip_runtime.h>
#include <float.h>
#include <math.h>

#define DIM 512
#define EPSN 1e-12f

typedef _Float16 f16x8 __attribute__((ext_vector_type(8)));
typedef float f32x4 __attribute__((ext_vector_type(4)));

// ---------------- wave (64-lane) sum ----------------
__device__ inline float wave_sum(float v) {
#pragma unroll
  for (int o = 32; o > 0; o >>= 1) v += __shfl_xor(v, o, 64);
  return v;
}

// one wave per emb row: eepair[j] = { sum(embn^2), 1/max(||emb_j||,eps) }
__global__ __launch_bounds__(256) void emb_norm_kernel(
    const float* __restrict__ emb, float2* __restrict__ eepair) {
  int row = blockIdx.x * 4 + (threadIdx.x >> 6);
  int lane = threadIdx.x & 63;
  const float* p = emb + (size_t)row * DIM;
  float x[8];
  float ss = 0.f;
#pragma unroll
  for (int i = 0; i < 8; ++i) { x[i] = p[i * 64 + lane]; ss += x[i] * x[i]; }
  ss = wave_sum(ss);
  float d = fmaxf(sqrtf(ss), EPSN);
  float ee = 0.f;
#pragma unroll
  for (int i = 0; i < 8; ++i) { float y = x[i] / d; ee += y * y; }
  ee = wave_sum(ee);
  if (lane == 0) eepair[row] = make_float2(ee, 1.0f / d);
}

// one wave per z row: zinv[n] = 1/max(||z_n||,eps)  (used by finalize only)
__global__ __launch_bounds__(256) void z_norm_kernel(
    const float* __restrict__ z, float* __restrict__ zinv) {
  int row = blockIdx.x * 4 + (threadIdx.x >> 6);
  int lane = threadIdx.x & 63;
  const float* p = z + (size_t)row * DIM;
  float ss = 0.f;
#pragma unroll
  for (int i = 0; i < 8; ++i) { float v = p[i * 64 + lane]; ss += v * v; }
  ss = wave_sum(ss);
  if (lane == 0) zinv[row] = 1.0f / fmaxf(sqrtf(ss), EPSN);
}

// ---------------- emb -> swizzled hi/lo fp16 of (embn * 1024) --------------
// swz layout: chunk c = (tile16 * 16 + kc) * 2 + half, each chunk = 64 lanes
// x 8 f16 (1 KB); element (lane = quad*16+col, j) = embn[tile16*16+col]
// [kc*32 + quad*8 + j] * 1024, split hi/lo. Normalized codebook (x1024 keeps
// the lo half out of fp16 subnormals) makes argmin(dist) == argmax(dot):
// ||zn||^2 is per-row constant and ||embn||^2 = 1 +- 2^-23, perturbation
// ~100x below the fp16 hi/lo dot error that already passes.
__global__ __launch_bounds__(256) void emb_split_kernel(
    const float* __restrict__ emb, const float2* __restrict__ eepair,
    _Float16* __restrict__ swz) {
  int g = blockIdx.x * 256 + threadIdx.x;  // = t*1024 + kc*64 + lane
  int lane = g & 63;
  int kc = (g >> 6) & 15;
  int t = g >> 10;
  int code = t * 16 + (lane & 15);
  int k0 = kc * 32 + (lane >> 4) * 8;
  float sc = 1024.0f * eepair[code].y;
  const float* src = emb + (size_t)code * DIM + k0;
  float4 a = *(const float4*)src;
  float4 b = *(const float4*)(src + 4);
  float v[8] = {a.x, a.y, a.z, a.w, b.x, b.y, b.z, b.w};
  f16x8 h, l;
#pragma unroll
  for (int k = 0; k < 8; ++k) {
    float vs = v[k] * sc;
    _Float16 hh = (_Float16)vs;
    h[k] = hh;
    l[k] = (_Float16)(vs - (float)hh);
  }
  size_t cbase = ((size_t)(t * 16 + kc) * 2) * 512;  // f16 units
  *(f16x8*)&swz[cbase + lane * 8] = h;
  *(f16x8*)&swz[cbase + 512 + lane * 8] = l;
}

// ---------------- MFMA dot + per-partition argmax ----------------
// r4 post-mortem: Ah/Al[2][16] = 256 VGPRs NEVER fit in the reported 168 --
// the A fragments were spilling to scratch in every prior round (explains
// FETCH_SIZE 98->327MB and why both counted-vmcnt and reg-staging changed
// nothing). Also gll16 is capped ~7 B/cyc per WORKGROUP (m97 cross-check:
// 22 B/cyc / 3 blocks), so at 1 block/CU it can't feed the MFMA floor.
//
// Fix both: 512 threads = 8 waves x 16 rows (A = Ah[16]+Al[16] = 128 VGPR,
// total ~190 -> spill-free under launch_bounds(512,2)); B staged by plain
// per-lane dwordx4 loads -> regs -> ds_write (T14), which rides the normal
// vmem scoreboard instead of the per-block DMA queue. Partition (blockIdx&7)
// keeps the B-stream 2.1MB (L2-class). Sync is ONLY __syncthreads() -- no
// inline-asm waitcnt anywhere (r4's nondeterminism lived there). Loads for
// tile t+2 are issued BEFORE compute(t) so the barrier's vmcnt(0) finds
// them already complete. 2 x 32KB LDS ping-pong; write(buf) and read(buf)
// are separated by a barrier in both directions.
#define MFMA16(A, B, C) __builtin_amdgcn_mfma_f32_16x16x32_f16(A, B, C, 0, 0, 0)

__global__ __launch_bounds__(512, 2) void dist_argmin_kernel(
    const float* __restrict__ z, const _Float16* __restrict__ swz,
    int ne, int nrows, float* __restrict__ pscore, int* __restrict__ pidx) {
  __shared__ __attribute__((aligned(16))) _Float16 Bb[2][16384];  // 2 x 32 KB

  const int tid = threadIdx.x;
  const int wave = tid >> 6;   // 0..7
  const int lane = tid & 63;
  const int col = lane & 15;
  const int quad = lane >> 4;
  const int part = blockIdx.x & 7;          // codebook partition
  const int r0 = (blockIdx.x >> 3) * 128 + wave * 16;
  const int ntl = ne >> 7;                  // 64 16-code tiles per partition
  const int tbase = part * ntl;             // global tile base

  float best[4] = {-FLT_MAX, -FLT_MAX, -FLT_MAX, -FLT_MAX};
  int bidx[4] = {0, 0, 0, 0};

  // ---- staging: wave covers 4 x 1KB chunks (32KB tile / 8 waves) ----
  f16x8 R0[4], R1[4];
  auto load_tile = [&](int t, f16x8* R) {
    const _Float16* gb =
        swz + (size_t)(tbase + t) * 16384 + (wave * 4) * 512 + lane * 8;
#pragma unroll
    for (int i = 0; i < 4; ++i) R[i] = *(const f16x8*)(gb + i * 512);
  };
  auto write_tile = [&](int buf, const f16x8* R) {
    _Float16* lb = &Bb[buf][(wave * 4) * 512 + lane * 8];
#pragma unroll
    for (int i = 0; i < 4; ++i) *(f16x8*)(lb + i * 512) = R[i];
  };

  // issue tiles 0,1 loads first; they complete under the A-fragment build
  load_tile(0, R0);
  load_tile(1, R1);

  // persistent A fragments (hi/lo) for this wave's 16 rows, from RAW z
  // (argmax of dot is invariant to the positive per-row scale zinv).
  // 16+16 f16x8 = 128 VGPRs -- fits, no spills (the r0-r4 bug).
  f16x8 Ah[16], Al[16];
  {
    const float* zp = z + (size_t)(r0 + col) * DIM + quad * 8;
#pragma unroll
    for (int kc = 0; kc < 16; ++kc) {
      float4 a = *(const float4*)(zp + kc * 32);
      float4 b = *(const float4*)(zp + kc * 32 + 4);
      float v[8] = {a.x, a.y, a.z, a.w, b.x, b.y, b.z, b.w};
#pragma unroll
      for (int k = 0; k < 8; ++k) {
        _Float16 h = (_Float16)v[k];
        Ah[kc][k] = h;
        Al[kc][k] = (_Float16)(v[k] - (float)h);
      }
    }
  }

  auto compute_tile = [&](int t, int buf) {
    f32x4 a0 = (f32x4){0.f, 0.f, 0.f, 0.f};
    f32x4 a1 = a0, a2 = a0;
    const _Float16* bp = &Bb[buf][lane * 8];
    __builtin_amdgcn_s_setprio(1);
#pragma unroll
    for (int kc = 0; kc < 16; ++kc) {
      f16x8 bh = *(const f16x8*)(bp + (kc * 2) * 512);
      f16x8 bl = *(const f16x8*)(bp + (kc * 2 + 1) * 512);
      a0 = MFMA16(Ah[kc], bh, a0);
      a1 = MFMA16(Al[kc], bh, a1);
      a2 = MFMA16(Ah[kc], bl, a2);
    }
    __builtin_amdgcn_s_setprio(0);
    // pure argmax; tiles ascend in j within the partition, so strict '>'
    // keeps the first (lowest) index on ties.
    int j = (tbase + t) * 16 + col;
#pragma unroll
    for (int i = 0; i < 4; ++i) {
      float d = a0[i] + a1[i] + a2[i];
      if (d > best[i]) { best[i] = d; bidx[i] = j; }
    }
  };

  // prologue: buf0 <- tile0 (compiler inserts the counted vmcnt for R0)
  write_tile(0, R0);
  __syncthreads();

  // 2-unrolled ping-pong, one __syncthreads per tile. Buffer safety: the
  // write to buf X is after compute(buf X)'s reads drained at the previous
  // barrier, and before the barrier that precedes the next compute(buf X).
  // Register safety: load overwrites R[x] only after R[x]'s ds_writes
  // drained at a previous barrier (lgkmcnt(0) inside __syncthreads).
  for (int t = 0; t < ntl; t += 2) {          // ntl = 64, even
    if (t + 2 < ntl) load_tile(t + 2, R0);    // hides under compute
    compute_tile(t, 0);
    write_tile(1, R1);                        // tile t+1 -> buf1
    __syncthreads();

    if (t + 3 < ntl) load_tile(t + 3, R1);
    compute_tile(t + 1, 1);
    if (t + 2 < ntl) write_tile(0, R0);       // tile t+2 -> buf0
    __syncthreads();
  }

  // merge across the 16 columns within each quad (xor 1,2,4,8 stays in quad)
#pragma unroll
  for (int i = 0; i < 4; ++i) {
    float bs = best[i];
    int bj = bidx[i];
#pragma unroll
    for (int offm = 1; offm < 16; offm <<= 1) {
      float os = __shfl_xor(bs, offm, 64);
      int oi = __shfl_xor(bj, offm, 64);
      if (os > bs || (os == bs && oi < bj)) { bs = os; bj = oi; }
    }
    if (col == 0) {
      int row = r0 + quad * 4 + i;
      pscore[(size_t)part * nrows + row] = bs;
      pidx[(size_t)part * nrows + row] = bj;
    }
  }
}

// fold the 8 per-partition partials per row; ascending p + strict '>'
// preserves global first-index semantics (partitions hold ascending ranges)
__global__ __launch_bounds__(256) void merge_kernel(
    const float* __restrict__ pscore, const int* __restrict__ pidx,
    int nrows, int* __restrict__ idxw, float* __restrict__ counts,
    float* __restrict__ out_idx) {
  int row = blockIdx.x * 256 + threadIdx.x;
  float bs = pscore[row];
  int bj = pidx[row];
#pragma unroll
  for (int p = 1; p < 8; ++p) {
    float s = pscore[(size_t)p * nrows + row];
    int j2 = pidx[(size_t)p * nrows + row];
    if (s > bs || (s == bs && j2 < bj)) { bs = s; bj = j2; }
  }
  idxw[row] = bj;
  out_idx[row] = (float)bj;
  atomicAdd(&counts[bj], 1.0f);
}

// one wave per row: z_q_st = normalize(q); per-block loss partial
__global__ __launch_bounds__(256) void finalize_rows_kernel(
    const float* __restrict__ z, const float* __restrict__ emb,
    const int* __restrict__ idxw, const float* __restrict__ zinv,
    float* __restrict__ out_zq, float* __restrict__ lpart) {
  __shared__ float red[4];
  int row = blockIdx.x * 4 + (threadIdx.x >> 6);
  int lane = threadIdx.x & 63;
  int j = idxw[row];
  const float* zp = z + (size_t)row * DIM;
  const float* qp = emb + (size_t)j * DIM;
  float zl[8], ql[8], tl[8];
  float st = 0.f, sq = 0.f;
#pragma unroll
  for (int i = 0; i < 8; ++i) {
    int k = i * 64 + lane;
    float zv = zp[k], qv = qp[k];
    float t = zv + (qv - zv);  // straight-through, literal arithmetic
    zl[i] = zv; ql[i] = qv; tl[i] = t;
    st += t * t;
    sq += qv * qv;
  }
  st = wave_sum(st);
  sq = wave_sum(sq);
  float dt = fmaxf(sqrtf(st), EPSN);
  float dq = fmaxf(sqrtf(sq), EPSN);
  float zi = zinv[row];
  float lp = 0.f;
#pragma unroll
  for (int i = 0; i < 8; ++i) {
    int k = i * 64 + lane;
    out_zq[(size_t)row * DIM + k] = tl[i] / dt;
    float e = ql[i] / dq - zl[i] * zi;
    lp += e * e;
  }
  lp = wave_sum(lp);
  if (lane == 0) red[threadIdx.x >> 6] = lp;
  __syncthreads();
  if (threadIdx.x == 0) lpart[blockIdx.x] = red[0] + red[1] + red[2] + red[3];
}

// single block: loss scalar (sum of block partials) + perplexity from counts
__global__ __launch_bounds__(256) void scalars_kernel(
    const float* __restrict__ counts, const float* __restrict__ lpart,
    int ne, int nblk, float inv_n, float inv_total,
    float* __restrict__ out_loss, float* __restrict__ out_perp) {
  __shared__ float red[8];
  int tid = threadIdx.x;
  float s = 0.f;
  for (int jj = tid; jj < ne; jj += 256) {
    float p = counts[jj] * inv_n;
    s += p * logf(p + 1e-10f);
  }
  float l = 0.f;
  for (int jj = tid; jj < nblk; jj += 256) l += lpart[jj];
  s = wave_sum(s);
  l = wave_sum(l);
  if ((tid & 63) == 0) { red[tid >> 6] = s; red[4 + (tid >> 6)] = l; }
  __syncthreads();
  if (tid == 0) {
    float t = red[0] + red[1] + red[2] + red[3];
    float lt = red[4] + red[5] + red[6] + red[7];
    *out_perp = expf(-t);
    *out_loss = 1.25f * lt * inv_total;  // (1+BETA)*mean, sg() identity fwd
  }
}

extern "C" void kernel_launch(void* const* d_in, const int* in_sizes, int n_in,
                              void* d_out, int out_size, void* d_ws, size_t ws_size,
                              hipStream_t stream) {
  const float* z = (const float*)d_in[0];
  const float* emb = (const float*)d_in[1];
  float* out = (float*)d_out;
  float* ws = (float*)d_ws;

  const int nrows = in_sizes[0] / DIM;  // 32768
  const int ne = in_sizes[1] / DIM;     // 8192
  const int nfin = nrows / 4;           // finalize blocks

  // workspace layout (floats)
  float2* eepair = (float2*)ws;                  // ne float2
  float* zinv = ws + 2 * ne;                     // nrows
  int* idxw = (int*)(ws + 2 * ne + nrows);       // nrows
  float* counts = ws + 2 * ne + 2 * nrows;       // ne
  float* lpart = counts + ne;                    // nfin
  float* pscore = lpart + nfin;                  // 8 * nrows
  int* pidx = (int*)(pscore + 8 * (size_t)nrows);// 8 * nrows
  _Float16* swz = (_Float16*)(pidx + 8 * (size_t)nrows);  // ne*1024 f16

  float* out_zq = out + 1;
  float* out_idx = out + 1 + (size_t)nrows * DIM;
  float* out_perp = out + (size_t)out_size - 1;

  hipMemsetAsync(counts, 0, ne * sizeof(float), stream);
  emb_norm_kernel<<<ne / 4, 256, 0, stream>>>(emb, eepair);
  z_norm_kernel<<<nrows / 4, 256, 0, stream>>>(z, zinv);
  emb_split_kernel<<<ne * 64 / 256, 256, 0, stream>>>(emb, eepair, swz);
  dist_argmin_kernel<<<(nrows / 128) * 8, 512, 0, stream>>>(z, swz, ne, nrows,
                                                            pscore, pidx);
  merge_kernel<<<nrows / 256, 256, 0, stream>>>(pscore, pidx, nrows,
                                                idxw, counts, out_idx);
  finalize_rows_kernel<<<nfin, 256, 0, stream>>>(z, emb, idxw, zinv,
                                                 out_zq, lpart);
  scalars_kernel<<<1, 256, 0, stream>>>(counts, lpart, ne, nfin,
                                        1.0f / (float)nrows,
                                        1.0f / (float)((size_t)nrows * DIM),
                                        out, out_perp);
}